// Round 6
// baseline (114.519 us; speedup 1.0000x reference)
//
#include <hip/hip_runtime.h>
#include <math.h>

// N=32768 tokens, B=32 batches, S=1024 keys/batch, H=512, OUT=32.
//
// Rank-2 collapse: score(i,j) = x_i^T (scale*Wq Wk^T) x_j  (2x2 M).
// w_i = softmax-weighted mean of x_j (2-vector); shift via analytic bound.
// BN folds into ABC[h] = {Wv0*g, Wv1*g, beta-mean*g}; P = PReLU(w0*A0+w1*A1+C).
// y = P @ Wout + bout as bf16 MFMA (16x16x32), Wout pre-swizzled into ws.
//
// R6 = R5 with the key-coverage bug fixed: each of the 16 slices owns 64 keys
// = 32 float4 (R5 iterated only 16 -> softmax over half the keys, absmax 2.09).
// 16 tokens/block, 2048 blocks -> 8 blocks/CU (32 waves/CU capacity).
// lane's token = lane&15 == MFMA A-frag m -> no shuffle redistribution.

#define H_DIM   512
#define OUT_DIM 32
#define S_LEN   1024
#define TOK     16
#define THREADS 256
#define NW 4

// ws layout (bytes)
#define WS_WOUT 0        // 32 KB: 32 frags x 64 lanes x 16 B bf16 B-fragments
#define WS_ABC  32768    // 8 KB: float4[512] {A0,A1,C,0}
#define WS_M    40960    // 16 B: scaled 2x2 M
#define WS_AMAX 40976    // 256 B: float2[32] per-batch {max|x0|, max|x1|}

#if __has_builtin(__builtin_amdgcn_exp2f)
#define EXP2(x) __builtin_amdgcn_exp2f(x)
#else
#define EXP2(x) exp2f(x)
#endif

typedef __attribute__((ext_vector_type(8))) short bf16x8;
typedef __attribute__((ext_vector_type(4))) float f32x4;

__device__ __forceinline__ unsigned int rne_bf16(float f) {
    unsigned int u = __float_as_uint(f);
    return (u + 0x7fffu + ((u >> 16) & 1u)) >> 16;
}
__device__ __forceinline__ unsigned int pack2bf16(float lo, float hi) {
    return rne_bf16(lo) | (rne_bf16(hi) << 16);
}

union frag_cast { unsigned int u[4]; int4 i4; bf16x8 v; };

// ---------------- setup: swizzle Wout->bf16 frags, fold BN, M, amax ----------
__global__ __launch_bounds__(256)
void setup_kernel(const float* __restrict__ x,
                  const float* __restrict__ Wq, const float* __restrict__ Wk,
                  const float* __restrict__ Wv,
                  const float* __restrict__ gam, const float* __restrict__ bet,
                  const float* __restrict__ mean, const float* __restrict__ var,
                  const float* __restrict__ Wout,
                  unsigned char* __restrict__ ws)
{
    const int t = threadIdx.x;
    if (blockIdx.x < 16) {
        // dst bf16-pair pi -> element d=2*pi: d = ((nt*16+s)*64 + l)*8 + j
        unsigned int* dst = (unsigned int*)(ws + WS_WOUT);
        #pragma unroll
        for (int k = 0; k < 2; ++k) {
            int pi = blockIdx.x * 512 + k * 256 + t;
            int d  = pi * 2;
            int fid = d >> 9;                 // nt*16+s, 0..31
            int l   = (d >> 3) & 63;
            int j   = d & 7;                  // even
            int nt  = fid >> 4;
            int s   = fid & 15;
            int h   = s * 32 + (l >> 4) * 8 + j;
            int o   = nt * 16 + (l & 15);
            float f0 = Wout[h * 32 + o];
            float f1 = Wout[(h + 1) * 32 + o];
            dst[pi] = pack2bf16(f0, f1);
        }
    } else {
        // ABC
        float4* abc = (float4*)(ws + WS_ABC);
        #pragma unroll
        for (int k = 0; k < 2; ++k) {
            int h = t + k * 256;
            float g = gam[h] * rsqrtf(var[h] + 1e-5f);
            abc[h] = make_float4(Wv[h] * g, Wv[H_DIM + h] * g,
                                 bet[h] - mean[h] * g, 0.f);
        }
        // M = scale * Wq Wk^T (wave 0 only)
        if (t < 64) {
            float m00 = 0.f, m01 = 0.f, m10 = 0.f, m11 = 0.f;
            #pragma unroll
            for (int k = 0; k < 8; ++k) {
                int h = t + k * 64;
                float a0 = Wq[h], a1 = Wq[H_DIM + h];
                float b0 = Wk[h], b1 = Wk[H_DIM + h];
                m00 = fmaf(a0, b0, m00); m01 = fmaf(a0, b1, m01);
                m10 = fmaf(a1, b0, m10); m11 = fmaf(a1, b1, m11);
            }
            #pragma unroll
            for (int off = 32; off >= 1; off >>= 1) {
                m00 += __shfl_xor(m00, off); m01 += __shfl_xor(m01, off);
                m10 += __shfl_xor(m10, off); m11 += __shfl_xor(m11, off);
            }
            if (t == 0) {
                const float scale = 0.044194173824159216f;  // 1/sqrt(512)
                float* m = (float*)(ws + WS_M);
                m[0] = m00 * scale; m[1] = m01 * scale;
                m[2] = m10 * scale; m[3] = m11 * scale;
            }
        }
        // per-batch amax: 8 threads per batch
        {
            int batch = t >> 3, sub = t & 7;
            const float4* xb = ((const float4*)x) + batch * 512;
            float a0 = 0.f, a1 = 0.f;
            for (int i = 0; i < 64; ++i) {
                float4 v = xb[sub + i * 8];
                a0 = fmaxf(a0, fmaxf(fabsf(v.x), fabsf(v.z)));
                a1 = fmaxf(a1, fmaxf(fabsf(v.y), fabsf(v.w)));
            }
            #pragma unroll
            for (int off = 4; off >= 1; off >>= 1) {
                a0 = fmaxf(a0, __shfl_xor(a0, off));
                a1 = fmaxf(a1, __shfl_xor(a1, off));
            }
            if (sub == 0)
                ((float2*)(ws + WS_AMAX))[batch] = make_float2(a0, a1);
        }
    }
}

// ---------------- main kernel ------------------------------------------------
__global__ __launch_bounds__(THREADS, 8)
void fused_attn_kernel(const float* __restrict__ x,
                       const float* __restrict__ prelu_a,
                       const float* __restrict__ bout,
                       const unsigned char* __restrict__ ws,
                       float* __restrict__ out)
{
    __shared__ float2 xs[S_LEN];            // 8 KB
    __shared__ float4 abcs[H_DIM];          // 8 KB
    __shared__ float redl[NW][16], redw0[NW][16], redw1[NW][16]; // 768 B
    __shared__ float yout[TOK][33];         // 2.1 KB, padded

    const int t    = threadIdx.x;
    const int lane = t & 63;
    const int q    = __builtin_amdgcn_readfirstlane(t >> 6);  // wave id 0..3
    const int b    = blockIdx.x >> 6;       // 64 blocks per batch
    const int tile = blockIdx.x & 63;       // token tile within batch

    // stage x and ABC into LDS; zero yout
    const float4* xg = (const float4*)(x + (size_t)b * (S_LEN * 2));
    float4* xs4 = (float4*)xs;
    xs4[t]       = xg[t];
    xs4[t + 256] = xg[t + 256];
    const float4* abcg = (const float4*)(ws + WS_ABC);
    abcs[t]       = abcg[t];
    abcs[t + 256] = abcg[t + 256];
    {
        float* yflat = &yout[0][0];
        #pragma unroll
        for (int i = t; i < TOK * 33; i += THREADS) yflat[i] = 0.f;
    }

    const float* mp = (const float*)(ws + WS_M);
    const float m00 = mp[0], m01 = mp[1], m10 = mp[2], m11 = mp[3];
    const float2 am = ((const float2*)(ws + WS_AMAX))[b];
    __syncthreads();

    // token = lane&15 (matches MFMA A-frag m); key-slice = q*4 + (lane>>4)
    const int tok = lane & 15;
    const float2 xt = xs[tile * TOK + tok];
    const float u0 = fmaf(xt.x, m00, xt.y * m10);
    const float u1 = fmaf(xt.x, m01, xt.y * m11);
    const float L2E = 1.4426950408889634f;
    const float bnd = fmaf(fabsf(u0), am.x, fabsf(u1) * am.y);
    const float u0L = u0 * L2E, u1L = u1 * L2E, nbL = -bnd * L2E;

    // fused softmax: 16 slices x 64 keys; this lane: 32 float4 (R5 bug: was 16)
    float l = 0.f, w0 = 0.f, w1 = 0.f;
    const int slice = q * 4 + (lane >> 4);
    const float4* kv = ((const float4*)xs) + slice * 32;
    #pragma unroll 8
    for (int i = 0; i < 32; ++i) {
        float4 k2 = kv[i];
        float e0 = EXP2(fmaf(u0L, k2.x, fmaf(u1L, k2.y, nbL)));
        float e1 = EXP2(fmaf(u0L, k2.z, fmaf(u1L, k2.w, nbL)));
        l += e0 + e1;
        w0 = fmaf(e0, k2.x, fmaf(e1, k2.z, w0));
        w1 = fmaf(e0, k2.y, fmaf(e1, k2.w, w1));
    }
    // wave-internal: sum the 4 lane-groups (token-preserving: tok = lane&15)
    l  += __shfl_xor(l, 16);  l  += __shfl_xor(l, 32);
    w0 += __shfl_xor(w0, 16); w0 += __shfl_xor(w0, 32);
    w1 += __shfl_xor(w1, 16); w1 += __shfl_xor(w1, 32);
    if (lane < 16) { redl[q][lane] = l; redw0[q][lane] = w0; redw1[q][lane] = w1; }
    __syncthreads();
    l = 0.f; w0 = 0.f; w1 = 0.f;
    #pragma unroll
    for (int w = 0; w < NW; ++w) {
        l  += redl[w][tok];
        w0 += redw0[w][tok];
        w1 += redw1[w][tok];
    }
    const float inv = 1.0f / l;
    const float w0t = w0 * inv, w1t = w1 * inv;   // already per-lane token m

    // ---- MFMA epilogue: wave q = k-quarter q (s in [q*4, q*4+4)) ----
    const float ap = prelu_a[0];
    const int quad = lane >> 4;
    f32x4 acc0 = {0.f, 0.f, 0.f, 0.f};
    f32x4 acc1 = {0.f, 0.f, 0.f, 0.f};
    const int4* bsrc = (const int4*)(ws + WS_WOUT);

    #pragma unroll
    for (int si = 0; si < 4; ++si) {
        const int s = q * 4 + si;
        frag_cast bf0, bf1;                 // coalesced 16B/lane, L2-resident
        bf0.i4 = bsrc[s * 64 + lane];
        bf1.i4 = bsrc[(16 + s) * 64 + lane];
        const int hbase = s * 32 + quad * 8;
        frag_cast af;
        #pragma unroll
        for (int jj = 0; jj < 4; ++jj) {
            float4 c0 = abcs[hbase + jj * 2];       // broadcast ds_read_b128
            float4 c1 = abcs[hbase + jj * 2 + 1];
            float z0 = fmaf(w0t, c0.x, fmaf(w1t, c0.y, c0.z));
            float z1 = fmaf(w0t, c1.x, fmaf(w1t, c1.y, c1.z));
            float p0 = fmaxf(z0, 0.f) + ap * fminf(z0, 0.f);   // PReLU
            float p1 = fmaxf(z1, 0.f) + ap * fminf(z1, 0.f);
            af.u[jj] = pack2bf16(p0, p1);
        }
        acc0 = __builtin_amdgcn_mfma_f32_16x16x32_bf16(af.v, bf0.v, acc0, 0, 0, 0);
        acc1 = __builtin_amdgcn_mfma_f32_16x16x32_bf16(af.v, bf1.v, acc1, 0, 0, 0);
    }

    // combine k-quarters: LDS float atomics (padded rows)
    // D layout: col = lane&15 (out), row = quad*4 + r (token)
    const int o0 = lane & 15;
    #pragma unroll
    for (int r = 0; r < 4; ++r) {
        const int tk = quad * 4 + r;
        atomicAdd(&yout[tk][o0],      acc0[r]);
        atomicAdd(&yout[tk][16 + o0], acc1[r]);
    }
    __syncthreads();

    // bias + coalesced store: thread t -> token t>>4, outputs (t&15)*2..+1
    {
        const size_t base = (size_t)(b * S_LEN + tile * TOK) * OUT_DIM;
        const int tk = t >> 4, o = (t & 15) * 2;
        const float2 b2 = ((const float2*)bout)[t & 15];
        float2 v;
        v.x = yout[tk][o]     + b2.x;
        v.y = yout[tk][o + 1] + b2.y;
        *(float2*)(out + base + (size_t)t * 2) = v;
    }
}

extern "C" void kernel_launch(void* const* d_in, const int* in_sizes, int n_in,
                              void* d_out, int out_size, void* d_ws, size_t ws_size,
                              hipStream_t stream) {
    const float* x    = (const float*)d_in[0];
    const float* Wq   = (const float*)d_in[2];
    const float* Wk   = (const float*)d_in[3];
    const float* Wv   = (const float*)d_in[4];
    const float* gam  = (const float*)d_in[5];
    const float* bet  = (const float*)d_in[6];
    const float* mean = (const float*)d_in[7];
    const float* var  = (const float*)d_in[8];
    const float* pa   = (const float*)d_in[9];
    const float* Wout = (const float*)d_in[10];
    const float* bo   = (const float*)d_in[11];
    float* out = (float*)d_out;
    unsigned char* ws = (unsigned char*)d_ws;

    hipLaunchKernelGGL(setup_kernel, dim3(17), dim3(256), 0, stream,
                       x, Wq, Wk, Wv, gam, bet, mean, var, Wout, ws);

    const int N = in_sizes[0] / 2;          // 32768 tokens
    const int blocks = N / TOK;             // 2048
    hipLaunchKernelGGL(fused_attn_kernel, dim3(blocks), dim3(THREADS), 0, stream,
                       x, pa, bo, ws, out);
}

// Round 7
// 93.295 us; speedup vs baseline: 1.2275x; 1.2275x over previous
//
#include <hip/hip_runtime.h>
#include <math.h>

// N=32768 tokens, B=32 batches, S=1024 keys/batch, H=512, OUT=32.
//
// Rank-2 collapse: score(i,j) = x_i^T (scale*Wq Wk^T) x_j  (2x2 M).
// w_i = softmax-weighted mean of x_j (2-vector). Softmax shift = 0: worst-case
// |score| <= |u||x| ~ 57 -> sum e^s <= ~8e26 < fp32 max; shift-invariant.
// BN folds into ABC[h] = {Wv0*g, Wv1*g, beta-mean*g}; P = PReLU(w0*A0+w1*A1+C).
// y = P @ Wout + bout as bf16 MFMA 16x16x32 (R3-proven layouts).
//
// R7 = R3 single-kernel: setup kernel eliminated (launch + serialization).
// Per block: ABC + M computed in prelude; Wout packed to bf16 B-fragments in
// LDS once per block (same flat layout R3's setup wrote to ws). 512 blocks x
// 256 thr, default launch bounds (R4/R6 showed VGPR caps/occupancy pushes lose).

#define H_DIM   512
#define OUT_DIM 32
#define S_LEN   1024
#define THREADS 256
#define NW 4

#if __has_builtin(__builtin_amdgcn_exp2f)
#define EXP2(x) __builtin_amdgcn_exp2f(x)
#else
#define EXP2(x) exp2f(x)
#endif

typedef __attribute__((ext_vector_type(8))) short bf16x8;
typedef __attribute__((ext_vector_type(4))) float f32x4;

__device__ __forceinline__ unsigned int rne_bf16(float f) {
    unsigned int u = __float_as_uint(f);
    return (u + 0x7fffu + ((u >> 16) & 1u)) >> 16;
}
__device__ __forceinline__ unsigned int pack2bf16(float lo, float hi) {
    return rne_bf16(lo) | (rne_bf16(hi) << 16);
}

union frag_cast { unsigned int u[4]; int4 i4; bf16x8 v; };

__global__ __launch_bounds__(THREADS)
void fused_attn_kernel(const float* __restrict__ x,
                       const float* __restrict__ Wq,
                       const float* __restrict__ Wk,
                       const float* __restrict__ Wv,
                       const float* __restrict__ bn_gamma,
                       const float* __restrict__ bn_beta,
                       const float* __restrict__ bn_mean,
                       const float* __restrict__ bn_var,
                       const float* __restrict__ prelu_a,
                       const float* __restrict__ Wout,
                       const float* __restrict__ bout,
                       float* __restrict__ out)
{
    __shared__ float2 xs[S_LEN];              // 8 KB
    __shared__ float4 abcs[H_DIM];            // 8 KB
    __shared__ unsigned int bfr[32 * 64 * 4]; // 32 KB: bf16 B-frags, R3 ws layout
    __shared__ float redl[NW][64], redw0[NW][64], redw1[NW][64]; // 3 KB
    __shared__ float mred[NW][4];

    const int t    = threadIdx.x;
    const int lane = t & 63;
    const int q    = __builtin_amdgcn_readfirstlane(t >> 6);  // wave id 0..3
    const int b    = blockIdx.x >> 4;         // 16 blocks per batch
    const int tile = blockIdx.x & 15;
    const float scale = 0.044194173824159216f;  // 1/sqrt(512)
    const float L2E   = 1.4426950408889634f;

    // ---- stage batch x ----
    const float4* xg = (const float4*)(x + (size_t)b * (S_LEN * 2));
    float4* xs4 = (float4*)xs;
    xs4[t]       = xg[t];
    xs4[t + 256] = xg[t + 256];

    // ---- fold BN into ABC (h = t, t+256) ----
    #pragma unroll
    for (int k = 0; k < 2; ++k) {
        int h = t + k * 256;
        float g = bn_gamma[h] * rsqrtf(bn_var[h] + 1e-5f);
        abcs[h] = make_float4(Wv[h] * g, Wv[H_DIM + h] * g,
                              bn_beta[h] - bn_mean[h] * g, 0.f);
    }

    // ---- M = Wq Wk^T partials ----
    {
        float m00 = 0.f, m01 = 0.f, m10 = 0.f, m11 = 0.f;
        #pragma unroll
        for (int k = 0; k < 2; ++k) {
            int h = t + k * 256;
            float a0 = Wq[h], a1 = Wq[H_DIM + h];
            float b0 = Wk[h], b1 = Wk[H_DIM + h];
            m00 = fmaf(a0, b0, m00); m01 = fmaf(a0, b1, m01);
            m10 = fmaf(a1, b0, m10); m11 = fmaf(a1, b1, m11);
        }
        #pragma unroll
        for (int off = 32; off >= 1; off >>= 1) {
            m00 += __shfl_xor(m00, off); m01 += __shfl_xor(m01, off);
            m10 += __shfl_xor(m10, off); m11 += __shfl_xor(m11, off);
        }
        if (lane == 0) {
            mred[q][0] = m00; mred[q][1] = m01;
            mred[q][2] = m10; mred[q][3] = m11;
        }
    }

    // ---- pack Wout -> bf16 B-frags in LDS (R3 setup's exact flat layout) ----
    // flat u32 index F = f*256 + l*4 + jj, f = nt*16+s, l = quad*16+c:
    //   bfr[F] = pack(Wout[s*32+quad*8+2jj][nt*16+c], Wout[s*32+quad*8+2jj+1][nt*16+c])
    // thread mapping i = k*256+t decodes c fastest for coalesced Wout reads.
    #pragma unroll
    for (int k = 0; k < 32; ++k) {
        int i    = k * 256 + t;
        int c    = i & 15;
        int jj   = (i >> 4) & 3;
        int quad = (i >> 6) & 3;
        int s    = (i >> 8) & 15;
        int nt   = (i >> 12) & 1;
        int h    = s * 32 + quad * 8 + 2 * jj;
        int o    = nt * 16 + c;
        float f0 = Wout[h * 32 + o];
        float f1 = Wout[(h + 1) * 32 + o];
        int F = (nt * 16 + s) * 256 + (quad * 16 + c) * 4 + jj;
        bfr[F] = pack2bf16(f0, f1);
    }
    __syncthreads();   // xs, abcs, mred, bfr all visible

    float m00 = (mred[0][0] + mred[1][0] + mred[2][0] + mred[3][0]) * scale;
    float m01 = (mred[0][1] + mred[1][1] + mred[2][1] + mred[3][1]) * scale;
    float m10 = (mred[0][2] + mred[1][2] + mred[2][2] + mred[3][2]) * scale;
    float m11 = (mred[0][3] + mred[1][3] + mred[2][3] + mred[3][3]) * scale;

    // ---- per-token u (lane = token), no shift (log2e folded) ----
    const float2 xt = xs[tile * 64 + lane];
    const float u0L = fmaf(xt.x, m00, xt.y * m10) * L2E;
    const float u1L = fmaf(xt.x, m01, xt.y * m11) * L2E;

    // ---- fused softmax pass: wave q covers keys [q*256, q*256+256) ----
    float l = 0.f, w0 = 0.f, w1 = 0.f;
    const float4* kv = ((const float4*)xs) + q * 128;
    #pragma unroll 4
    for (int i = 0; i < 128; ++i) {
        float4 k2 = kv[i];                  // wave-uniform addr -> broadcast
        float e0 = EXP2(fmaf(u0L, k2.x, u1L * k2.y));
        float e1 = EXP2(fmaf(u0L, k2.z, u1L * k2.w));
        l += e0 + e1;
        w0 = fmaf(e0, k2.x, fmaf(e1, k2.z, w0));
        w1 = fmaf(e0, k2.y, fmaf(e1, k2.w, w1));
    }
    redl[q][lane] = l; redw0[q][lane] = w0; redw1[q][lane] = w1;
    __syncthreads();
    l  = redl[0][lane]  + redl[1][lane]  + redl[2][lane]  + redl[3][lane];
    w0 = redw0[0][lane] + redw0[1][lane] + redw0[2][lane] + redw0[3][lane];
    w1 = redw1[0][lane] + redw1[1][lane] + redw1[2][lane] + redw1[3][lane];
    const float inv = 1.0f / l;
    w0 *= inv; w1 *= inv;

    // redistribute: wave q's MFMA tile = tokens q*16..q*16+15; m = lane&15
    const int src = q * 16 + (lane & 15);
    const float w0t = __shfl(w0, src);
    const float w1t = __shfl(w1, src);

    // ---- MFMA epilogue: y[16 tok x 32 out] = P[16 x 512] @ Wout[512 x 32] ----
    const float ap = prelu_a[0];
    const int quad = lane >> 4;
    f32x4 acc0 = {0.f, 0.f, 0.f, 0.f};
    f32x4 acc1 = {0.f, 0.f, 0.f, 0.f};
    const int4* bsrc = (const int4*)bfr;

    for (int s = 0; s < 16; ++s) {
        frag_cast bf0, bf1;                 // ds_read_b128, 2-way alias = free
        bf0.i4 = bsrc[s * 64 + lane];
        bf1.i4 = bsrc[(16 + s) * 64 + lane];
        const int hbase = s * 32 + quad * 8;
        frag_cast af;
        #pragma unroll
        for (int jj = 0; jj < 4; ++jj) {
            float4 c0 = abcs[hbase + jj * 2];       // broadcast ds_read_b128
            float4 c1 = abcs[hbase + jj * 2 + 1];
            float z0 = fmaf(w0t, c0.x, fmaf(w1t, c0.y, c0.z));
            float z1 = fmaf(w0t, c1.x, fmaf(w1t, c1.y, c1.z));
            float p0 = fmaxf(z0, 0.f) + ap * fminf(z0, 0.f);   // PReLU
            float p1 = fmaxf(z1, 0.f) + ap * fminf(z1, 0.f);
            af.u[jj] = pack2bf16(p0, p1);
        }
        acc0 = __builtin_amdgcn_mfma_f32_16x16x32_bf16(af.v, bf0.v, acc0, 0, 0, 0);
        acc1 = __builtin_amdgcn_mfma_f32_16x16x32_bf16(af.v, bf1.v, acc1, 0, 0, 0);
    }

    // ---- store: D col=lane&15 (out), row=quad*4+r (token) ----
    const size_t base = (size_t)(b * S_LEN + tile * 64) * OUT_DIM;
    const int o0 = lane & 15;
    const float bo0 = bout[o0], bo1 = bout[16 + o0];
    #pragma unroll
    for (int r = 0; r < 4; ++r) {
        const int tt = q * 16 + quad * 4 + r;
        out[base + tt * 32 + o0]      = acc0[r] + bo0;
        out[base + tt * 32 + 16 + o0] = acc1[r] + bo1;
    }
}

extern "C" void kernel_launch(void* const* d_in, const int* in_sizes, int n_in,
                              void* d_out, int out_size, void* d_ws, size_t ws_size,
                              hipStream_t stream) {
    const float* x    = (const float*)d_in[0];
    const float* Wq   = (const float*)d_in[2];
    const float* Wk   = (const float*)d_in[3];
    const float* Wv   = (const float*)d_in[4];
    const float* gam  = (const float*)d_in[5];
    const float* bet  = (const float*)d_in[6];
    const float* mean = (const float*)d_in[7];
    const float* var  = (const float*)d_in[8];
    const float* pa   = (const float*)d_in[9];
    const float* Wout = (const float*)d_in[10];
    const float* bo   = (const float*)d_in[11];
    float* out = (float*)d_out;

    const int N = in_sizes[0] / 2;          // 32768 tokens
    const int blocks = N / 64;              // 512
    hipLaunchKernelGGL(fused_attn_kernel, dim3(blocks), dim3(THREADS), 0, stream,
                       x, Wq, Wk, Wv, gam, bet, mean, var, pa, Wout, bo, out);
}